// Round 1
// baseline (130.239 us; speedup 1.0000x reference)
//
#include <hip/hip_runtime.h>
#include <hip/hip_bf16.h>
#include <math.h>

#define BATCH 256
#define SEQL  4096
#define DIMC  256
#define NPAT  160
#define CNT   (BATCH * SEQL)     // per-stream element count (over B,L)
#define EPS   1e-3f

// Extended pattern index for position t of a bit row (bits[i] in {0,1}).
// q = type*32 + 5-bit window, padded taps forced to 0-bit.
// type: 0 interior, 1: t==0, 2: t==1, 3: t==L-2, 4: t==L-1
__device__ __forceinline__ int pat_q(const unsigned char* bits, int t) {
    unsigned b = 0;
#pragma unroll
    for (int k = 0; k < 5; ++k) {
        int pos = t + k - 2;
        unsigned v = (pos >= 0 && pos < SEQL) ? (unsigned)bits[pos] : 0u;
        b |= v << k;
    }
    int type;
    if (t >= 2 && t < SEQL - 2) type = 0;
    else if (t == 0) type = 1;
    else if (t == 1) type = 2;
    else if (t == SEQL - 2) type = 3;
    else type = 4;
    return type * 32 + (int)b;
}

// padded-tap mask per type
__device__ __forceinline__ int pad_mask(int type) {
    return (type == 0) ? 0 : (type == 1) ? 3 : (type == 2) ? 1 : (type == 3) ? 16 : 24;
}

// ---------------- Kernel A: pattern histograms (direct + interleaved) ----------
__global__ __launch_bounds__(256) void k_hist(const float* __restrict__ x,
                                              const int* __restrict__ perms,
                                              unsigned int* __restrict__ hist) {
    __shared__ unsigned char xb[SEQL];
    __shared__ unsigned char xbI[SEQL];
    __shared__ unsigned int h[2 * NPAT];
    const int b = blockIdx.x, tid = threadIdx.x;
    for (int i = tid; i < 2 * NPAT; i += 256) h[i] = 0;
    const float* xr = x + (size_t)b * SEQL;
    const int* pr = perms + (size_t)b * SEQL;
    for (int i = tid; i < SEQL; i += 256) xb[i] = xr[i] > 0.5f ? 1 : 0;
    __syncthreads();
    for (int i = tid; i < SEQL; i += 256) xbI[i] = xb[pr[i]];
    __syncthreads();
    for (int t = tid; t < SEQL; t += 256) {
        atomicAdd(&h[pat_q(xb, t)], 1u);
        atomicAdd(&h[NPAT + pat_q(xbI, t)], 1u);
    }
    __syncthreads();
    for (int i = tid; i < 2 * NPAT; i += 256)
        if (h[i]) atomicAdd(&hist[i], h[i]);
}

// ---------------- Kernel B1: per-stream BN stats + e-table ---------------------
struct PtrPack { const float* p[18]; };  // per stream: Wc, bc, g, be, Wf, bf

__global__ __launch_bounds__(256) void k_etab(PtrPack pk,
                                              const unsigned int* __restrict__ hist,
                                              float* __restrict__ e_tab) {
    const int j = blockIdx.x, c = threadIdx.x;
    const float* Wc = pk.p[6 * j + 0];
    const float* bc = pk.p[6 * j + 1];
    const float* g  = pk.p[6 * j + 2];
    const float* be = pk.p[6 * j + 3];
    const float* Wf = pk.p[6 * j + 4];
    const float  bf = pk.p[6 * j + 5][0];
    const unsigned int* hj = hist + (j == 2 ? NPAT : 0);

    __shared__ float sw[5 * DIMC], sbc[DIMC], ssc[DIMC], sof[DIMC], swf[DIMC];
    __shared__ unsigned int sh[NPAT];
    float w[5];
#pragma unroll
    for (int k = 0; k < 5; ++k) { w[k] = Wc[k * DIMC + c]; sw[k * DIMC + c] = w[k]; }
    const float bcc = bc[c];
    sbc[c] = bcc;
    swf[c] = Wf[c];
    if (c < NPAT) sh[c] = hj[c];
    __syncthreads();

    // channel-c population stats from histogram (exact, double accum)
    double S = 0.0, SS = 0.0;
    for (int q = 0; q < NPAT; ++q) {
        const unsigned n = sh[q];
        if (!n) continue;
        const int type = q >> 5, bits = q & 31;
        const int pm = pad_mask(type);
        float y = bcc;
#pragma unroll
        for (int k = 0; k < 5; ++k) {
            const float tv = ((pm >> k) & 1) ? 0.0f : (((bits >> k) & 1) ? 1.0f : -1.0f);
            y += tv * w[k];
        }
        S  += (double)n * (double)y;
        SS += (double)n * (double)y * (double)y;
    }
    const double m = S / (double)CNT;
    const double v = SS / (double)CNT - m * m;
    const float scale = g[c] * rsqrtf((float)v + EPS);
    ssc[c] = scale;
    sof[c] = be[c] - scale * (float)m;
    __syncthreads();

    if (c < NPAT) {
        const int q = c;
        const int type = q >> 5, bits = q & 31;
        const int pm = pad_mask(type);
        float tap[5];
#pragma unroll
        for (int k = 0; k < 5; ++k)
            tap[k] = ((pm >> k) & 1) ? 0.0f : (((bits >> k) & 1) ? 1.0f : -1.0f);
        float e = 0.0f;
        for (int cc = 0; cc < DIMC; ++cc) {
            float y = sbc[cc];
#pragma unroll
            for (int k = 0; k < 5; ++k) y += tap[k] * sw[k * DIMC + cc];
            const float bn = ssc[cc] * y + sof[cc];
            const float a = bn > 0.0f ? bn : expm1f(bn);
            e += a * swf[cc];
        }
        e_tab[j * NPAT + q] = e + bf;
    }
}

// ---------------- Kernel B2: middle+output units -> final output table ---------
__global__ __launch_bounds__(512) void k_outtab(const unsigned int* __restrict__ hist,
                                                const float* __restrict__ e_tab,
                                                const float* __restrict__ Wm,
                                                const float* __restrict__ gm,
                                                const float* __restrict__ bem,
                                                const float* __restrict__ Wo,
                                                const float* __restrict__ bo,
                                                const float* __restrict__ go,
                                                const float* __restrict__ beo,
                                                float* __restrict__ out_tab) {
    const int tid = threadIdx.x;
    __shared__ double red[512];
    __shared__ float se[3 * NPAT];
    __shared__ unsigned int sn[3 * NPAT];
    __shared__ float sA[DIMC], sB[DIMC], sWo0[DIMC], sWo1[DIMC];

    for (int i = tid; i < 3 * NPAT; i += 512) {
        se[i] = e_tab[i];
        sn[i] = hist[(i >= 2 * NPAT) ? (i - NPAT) : (i % NPAT)];
    }
    __syncthreads();

    // yt mean/var (population over 3*B*L elements) from weighted tables
    double s1 = 0.0, s2 = 0.0;
    for (int i = tid; i < 3 * NPAT; i += 512) {
        const double n = (double)sn[i], e = (double)se[i];
        s1 += n * e;
        s2 += n * e * e;
    }
    red[tid] = s1; __syncthreads();
    for (int o = 256; o > 0; o >>= 1) { if (tid < o) red[tid] += red[tid + o]; __syncthreads(); }
    const double sum1 = red[0]; __syncthreads();
    red[tid] = s2; __syncthreads();
    for (int o = 256; o > 0; o >>= 1) { if (tid < o) red[tid] += red[tid + o]; __syncthreads(); }
    const double sum2 = red[0]; __syncthreads();
    const double mean_yt = sum1 / (3.0 * (double)CNT);
    const double var_yt  = sum2 / (3.0 * (double)CNT) - mean_yt * mean_yt;

    // middle coding unit: mo_c = elu(A_c*(u - mean_yt) + B_c)   (bm cancels in BN)
    if (tid < DIMC) {
        const float wm = Wm[tid];
        sA[tid] = gm[tid] * wm * rsqrtf(wm * wm * (float)var_yt + EPS);
        sB[tid] = bem[tid];
        sWo0[tid] = Wo[tid * 2 + 0];
        sWo1[tid] = Wo[tid * 2 + 1];
    }
    __syncthreads();

    float pre0 = 0.0f, pre1 = 0.0f;
    if (tid < 3 * NPAT) {
        const float du = se[tid] - (float)mean_yt;
        float a0 = bo[0], a1 = bo[1];
        for (int c = 0; c < DIMC; ++c) {
            const float tz = sA[c] * du + sB[c];
            const float mo = tz > 0.0f ? tz : expm1f(tz);
            a0 += mo * sWo0[c];
            a1 += mo * sWo1[c];
        }
        pre0 = a0; pre1 = a1;
    }
    const double nw = (tid < 3 * NPAT) ? (double)sn[tid] : 0.0;

    red[tid] = nw * (double)pre0; __syncthreads();
    for (int o = 256; o > 0; o >>= 1) { if (tid < o) red[tid] += red[tid + o]; __syncthreads(); }
    const double sm0 = red[0]; __syncthreads();
    red[tid] = nw * (double)pre0 * (double)pre0; __syncthreads();
    for (int o = 256; o > 0; o >>= 1) { if (tid < o) red[tid] += red[tid + o]; __syncthreads(); }
    const double sq0 = red[0]; __syncthreads();
    red[tid] = nw * (double)pre1; __syncthreads();
    for (int o = 256; o > 0; o >>= 1) { if (tid < o) red[tid] += red[tid + o]; __syncthreads(); }
    const double sm1 = red[0]; __syncthreads();
    red[tid] = nw * (double)pre1 * (double)pre1; __syncthreads();
    for (int o = 256; o > 0; o >>= 1) { if (tid < o) red[tid] += red[tid + o]; __syncthreads(); }
    const double sq1 = red[0]; __syncthreads();

    const double m0 = sm0 / (3.0 * (double)CNT);
    const double v0 = sq0 / (3.0 * (double)CNT) - m0 * m0;
    const double m1 = sm1 / (3.0 * (double)CNT);
    const double v1 = sq1 / (3.0 * (double)CNT) - m1 * m1;

    if (tid < 3 * NPAT) {
        const float sc0 = go[0] * rsqrtf((float)v0 + EPS);
        const float sc1 = go[1] * rsqrtf((float)v1 + EPS);
        out_tab[tid * 2 + 0] = sc0 * (pre0 - (float)m0) + beo[0];
        out_tab[tid * 2 + 1] = sc1 * (pre1 - (float)m1) + beo[1];
    }
}

// ---------------- Kernel C: recompute patterns, write final output -------------
__global__ __launch_bounds__(256) void k_write(const float* __restrict__ x,
                                               const int* __restrict__ perms,
                                               const float* __restrict__ out_tab,
                                               float* __restrict__ out) {
    __shared__ unsigned char xb[SEQL];
    __shared__ unsigned char xbI[SEQL];
    __shared__ float tb[3 * NPAT * 2];
    const int b = blockIdx.x, tid = threadIdx.x;
    for (int i = tid; i < 3 * NPAT * 2; i += 256) tb[i] = out_tab[i];
    const float* xr = x + (size_t)b * SEQL;
    const int* pr = perms + (size_t)b * SEQL;
    for (int i = tid; i < SEQL; i += 256) xb[i] = xr[i] > 0.5f ? 1 : 0;
    __syncthreads();
    for (int i = tid; i < SEQL; i += 256) xbI[i] = xb[pr[i]];
    __syncthreads();
    float* ob = out + (size_t)b * (3 * SEQL * 2);
    for (int t = tid; t < SEQL; t += 256) {
        const int qd = pat_q(xb, t);
        const int qp = pat_q(xbI, t);
        const float2 v0 = *(const float2*)&tb[(0 * NPAT + qd) * 2];
        const float2 v1 = *(const float2*)&tb[(1 * NPAT + qd) * 2];
        const float2 v2 = *(const float2*)&tb[(2 * NPAT + qp) * 2];
        float2* o = (float2*)(ob + (size_t)t * 6);
        o[0] = v0; o[1] = v1; o[2] = v2;
    }
}

extern "C" void kernel_launch(void* const* d_in, const int* in_sizes, int n_in,
                              void* d_out, int out_size, void* d_ws, size_t ws_size,
                              hipStream_t stream) {
    (void)in_sizes; (void)n_in; (void)out_size; (void)ws_size;
    const float* x = (const float*)d_in[0];
    const int* perms = (const int*)d_in[1];

    // ws layout: [0,1280) u32 hist[320]; [1280,3200) f32 e_tab[480];
    //            [3200,7040) f32 out_tab[960]
    unsigned int* hist = (unsigned int*)d_ws;
    float* e_tab  = (float*)((char*)d_ws + 1280);
    float* out_tab = (float*)((char*)d_ws + 3200);

    hipMemsetAsync(d_ws, 0, 1280, stream);
    k_hist<<<BATCH, 256, 0, stream>>>(x, perms, hist);

    PtrPack pk;
    for (int j = 0; j < 3; ++j)
        for (int s = 0; s < 6; ++s)
            pk.p[6 * j + s] = (const float*)d_in[2 + 6 * j + s];
    k_etab<<<3, 256, 0, stream>>>(pk, hist, e_tab);

    k_outtab<<<1, 512, 0, stream>>>(hist, e_tab,
                                    (const float*)d_in[20],  // Wm
                                    (const float*)d_in[22],  // gm
                                    (const float*)d_in[23],  // bem
                                    (const float*)d_in[24],  // Wo
                                    (const float*)d_in[25],  // bo
                                    (const float*)d_in[26],  // go
                                    (const float*)d_in[27],  // beo
                                    out_tab);

    k_write<<<BATCH, 256, 0, stream>>>(x, perms, out_tab, (float*)d_out);
}

// Round 2
// 68.876 us; speedup vs baseline: 1.8909x; 1.8909x over previous
//
#include <hip/hip_runtime.h>
#include <hip/hip_bf16.h>
#include <math.h>

#define BATCH 256
#define SEQL  4096
#define DIMC  256
#define NPAT  160
#define CNT   (BATCH * SEQL)     // per-stream element count (over B,L)
#define EPS   1e-3f

// Extended pattern index for position t of a bit row (bits[i] in {0,1}).
// q = type*32 + 5-bit window, padded taps forced to 0-bit.
// type: 0 interior, 1: t==0, 2: t==1, 3: t==L-2, 4: t==L-1
__device__ __forceinline__ int pat_q(const unsigned char* bits, int t) {
    unsigned b = 0;
#pragma unroll
    for (int k = 0; k < 5; ++k) {
        int pos = t + k - 2;
        unsigned v = (pos >= 0 && pos < SEQL) ? (unsigned)bits[pos] : 0u;
        b |= v << k;
    }
    int type;
    if (t >= 2 && t < SEQL - 2) type = 0;
    else if (t == 0) type = 1;
    else if (t == 1) type = 2;
    else if (t == SEQL - 2) type = 3;
    else type = 4;
    return type * 32 + (int)b;
}

__device__ __forceinline__ int pad_mask(int type) {
    return (type == 0) ? 0 : (type == 1) ? 3 : (type == 2) ? 1 : (type == 3) ? 16 : 24;
}

// tap value for extended-pattern q, index k in [0,6): k==5 is the constant 1.
__device__ __forceinline__ float tap6(int q, int k) {
    if (k == 5) return 1.0f;
    const int type = q >> 5, bits = q & 31;
    const int pm = pad_mask(type);
    if ((pm >> k) & 1) return 0.0f;
    return ((bits >> k) & 1) ? 1.0f : -1.0f;
}

// triangular index of pair (k,l), k<=l, 6x6 symmetric, row-major upper
__device__ __forceinline__ int tri_idx(int k, int l) {
    return k * 6 - (k * (k - 1)) / 2 + (l - k);
}

__device__ __forceinline__ float fast_elu(float x) {
    return x > 0.0f ? x : (__expf(x) - 1.0f);
}

// ---------------- Kernel A: pattern histograms (direct + interleaved) ----------
__global__ __launch_bounds__(256) void k_hist(const float* __restrict__ x,
                                              const int* __restrict__ perms,
                                              unsigned int* __restrict__ hist) {
    __shared__ unsigned char xb[SEQL];
    __shared__ unsigned char xbI[SEQL];
    __shared__ unsigned int h[2 * NPAT];
    const int b = blockIdx.x, tid = threadIdx.x;
    for (int i = tid; i < 2 * NPAT; i += 256) h[i] = 0;
    const float* xr = x + (size_t)b * SEQL;
    const int* pr = perms + (size_t)b * SEQL;
    for (int i = tid; i < SEQL; i += 256) xb[i] = xr[i] > 0.5f ? 1 : 0;
    __syncthreads();
    for (int i = tid; i < SEQL; i += 256) xbI[i] = xb[pr[i]];
    __syncthreads();
    for (int t = tid; t < SEQL; t += 256) {
        atomicAdd(&h[pat_q(xb, t)], 1u);
        atomicAdd(&h[NPAT + pat_q(xbI, t)], 1u);
    }
    __syncthreads();
    for (int i = tid; i < 2 * NPAT; i += 256)
        if (h[i]) atomicAdd(&hist[i], h[i]);
}

// ---------------- Kernel B1: wave-parallel e-table -----------------------------
// grid = 120 blocks: blocks [40j, 40j+40) handle stream j; each block's 4 waves
// compute e(q) for q = (blk%40)*4 + waveIdx.
struct PtrPack { const float* p[18]; };  // per stream: Wc, bc, g, be, Wf, bf

__global__ __launch_bounds__(256) void k_etab(PtrPack pk,
                                              const unsigned int* __restrict__ hist,
                                              float* __restrict__ e_tab) {
    const int tid = threadIdx.x;
    const int j = blockIdx.x / 40;
    const int qbase = (blockIdx.x % 40) * 4;
    const float* Wc = pk.p[6 * j + 0];
    const float* bc = pk.p[6 * j + 1];
    const float* g  = pk.p[6 * j + 2];
    const float* be = pk.p[6 * j + 3];
    const float* Wf = pk.p[6 * j + 4];
    const float  bf = pk.p[6 * j + 5][0];
    const unsigned int* hj = hist + (j == 2 ? NPAT : 0);

    __shared__ float sn[NPAT];            // counts (integer-exact in f32)
    __shared__ float m6part[21][8];
    __shared__ float sM6[21];             // raw second-moment sums (exact)
    __shared__ float sa[5][DIMC];         // scale*w_k
    __shared__ float sb[DIMC];            // scale*(bc - mean) + be
    __shared__ float swf[DIMC];

    if (tid < NPAT) sn[tid] = (float)hj[tid];
    __syncthreads();

    // M6 partials: 21 entries x 8 bin-chunks
    if (tid < 168) {
        const int e = tid >> 3, part = tid & 7;
        int k = 0, rem = e;
        while (rem > 5 - k) { rem -= 6 - k; ++k; }
        const int l = k + rem;
        float S = 0.0f;
        for (int q = part * 20; q < part * 20 + 20; ++q)
            S += sn[q] * tap6(q, k) * tap6(q, l);
        m6part[e][part] = S;
    }
    __syncthreads();
    if (tid < 21) {
        float S = 0.0f;
#pragma unroll
        for (int p = 0; p < 8; ++p) S += m6part[tid][p];
        sM6[tid] = S;
    }
    __syncthreads();

    // per-channel BN coefficients (exact stats via quadratic form)
    {
        const int c = tid;  // 256 threads, 256 channels
        float w6[6];
#pragma unroll
        for (int k = 0; k < 5; ++k) w6[k] = Wc[k * DIMC + c];
        w6[5] = bc[c];
        double Ey = 0.0, Ey2 = 0.0;
        int e = 0;
        for (int k = 0; k < 6; ++k) {
            Ey += (double)w6[k] * (double)sM6[tri_idx(k, 5)];
            for (int l = k; l < 6; ++l, ++e) {
                const double p = (double)w6[k] * (double)w6[l] * (double)sM6[e];
                Ey2 += (l == k) ? p : 2.0 * p;
            }
        }
        const double mean = Ey / (double)CNT;
        const double var = Ey2 / (double)CNT - mean * mean;
        const float scale = g[c] * rsqrtf((float)var + EPS);
#pragma unroll
        for (int k = 0; k < 5; ++k) sa[k][c] = scale * w6[k];
        sb[c] = scale * (w6[5] - (float)mean) + be[c];
        swf[c] = Wf[c];
    }
    __syncthreads();

    // one wave per pattern
    const int q = qbase + (tid >> 6);
    const int lane = tid & 63;
    float tk[5];
#pragma unroll
    for (int k = 0; k < 5; ++k) tk[k] = tap6(q, k);
    float acc = 0.0f;
#pragma unroll
    for (int i = 0; i < 4; ++i) {
        const int c = lane + 64 * i;
        float bn = sb[c];
#pragma unroll
        for (int k = 0; k < 5; ++k) bn += tk[k] * sa[k][c];
        acc += fast_elu(bn) * swf[c];
    }
#pragma unroll
    for (int off = 32; off; off >>= 1) acc += __shfl_xor(acc, off);
    if (lane == 0) e_tab[j * NPAT + q] = acc + bf;
}

// ---------------- Kernel B2: middle+output units -> final output table ---------
__global__ __launch_bounds__(1024) void k_outtab(const unsigned int* __restrict__ hist,
                                                 const float* __restrict__ e_tab,
                                                 const float* __restrict__ Wm,
                                                 const float* __restrict__ gm,
                                                 const float* __restrict__ bem,
                                                 const float* __restrict__ Wo,
                                                 const float* __restrict__ bo,
                                                 const float* __restrict__ go,
                                                 const float* __restrict__ beo,
                                                 float* __restrict__ out_tab) {
    const int tid = threadIdx.x;
    const int lane = tid & 63, wv = tid >> 6;  // 16 waves

    __shared__ float se[3 * NPAT];
    __shared__ float snn[3 * NPAT];
    __shared__ float sA[DIMC], sB[DIMC], sWo0[DIMC], sWo1[DIMC];
    __shared__ float spre0[3 * NPAT], spre1[3 * NPAT];
    __shared__ double wpart[16][4];
    __shared__ double dstat[6];

    if (tid < 3 * NPAT) {
        se[tid] = e_tab[tid];
        snn[tid] = (float)hist[(tid >= 2 * NPAT) ? (tid - NPAT) : (tid % NPAT)];
    }
    __syncthreads();

    // yt mean/var: weighted f64 reduction over 480 bins
    {
        double d1 = 0.0, d2 = 0.0;
        if (tid < 3 * NPAT) {
            const double n = (double)snn[tid], e = (double)se[tid];
            d1 = n * e; d2 = n * e * e;
        }
#pragma unroll
        for (int off = 32; off; off >>= 1) {
            d1 += __shfl_xor(d1, off);
            d2 += __shfl_xor(d2, off);
        }
        if (lane == 0) { wpart[wv][0] = d1; wpart[wv][1] = d2; }
        __syncthreads();
        if (wv == 0) {
            double a = (lane < 16) ? wpart[lane][0] : 0.0;
            double b = (lane < 16) ? wpart[lane][1] : 0.0;
#pragma unroll
            for (int off = 8; off; off >>= 1) {
                a += __shfl_xor(a, off);
                b += __shfl_xor(b, off);
            }
            if (lane == 0) { dstat[0] = a; dstat[1] = b; }
        }
        __syncthreads();
    }
    const double mean_yt = dstat[0] / (3.0 * (double)CNT);
    const double var_yt  = dstat[1] / (3.0 * (double)CNT) - mean_yt * mean_yt;

    if (tid < DIMC) {
        const float wm = Wm[tid];
        sA[tid] = gm[tid] * wm * rsqrtf(wm * wm * (float)var_yt + EPS);
        sB[tid] = bem[tid];
        sWo0[tid] = Wo[tid * 2 + 0];
        sWo1[tid] = Wo[tid * 2 + 1];
    }
    __syncthreads();

    // wave-parallel pre-activations per pattern
    const float bo0 = bo[0], bo1 = bo[1];
    for (int idx = wv; idx < 3 * NPAT; idx += 16) {
        const float du = se[idx] - (float)mean_yt;
        float a0 = 0.0f, a1 = 0.0f;
#pragma unroll
        for (int i = 0; i < 4; ++i) {
            const int c = lane + 64 * i;
            const float mo = fast_elu(sA[c] * du + sB[c]);
            a0 += mo * sWo0[c];
            a1 += mo * sWo1[c];
        }
#pragma unroll
        for (int off = 32; off; off >>= 1) {
            a0 += __shfl_xor(a0, off);
            a1 += __shfl_xor(a1, off);
        }
        if (lane == 0) { spre0[idx] = a0 + bo0; spre1[idx] = a1 + bo1; }
    }
    __syncthreads();

    // output BN stats: 4 weighted f64 sums
    {
        double v[4] = {0.0, 0.0, 0.0, 0.0};
        if (tid < 3 * NPAT) {
            const double n = (double)snn[tid];
            const double p0 = (double)spre0[tid], p1 = (double)spre1[tid];
            v[0] = n * p0; v[1] = n * p0 * p0; v[2] = n * p1; v[3] = n * p1 * p1;
        }
#pragma unroll
        for (int off = 32; off; off >>= 1)
#pragma unroll
            for (int s = 0; s < 4; ++s) v[s] += __shfl_xor(v[s], off);
        if (lane == 0)
#pragma unroll
            for (int s = 0; s < 4; ++s) wpart[wv][s] = v[s];
        __syncthreads();
        if (wv == 0) {
            double a[4];
#pragma unroll
            for (int s = 0; s < 4; ++s) a[s] = (lane < 16) ? wpart[lane][s] : 0.0;
#pragma unroll
            for (int off = 8; off; off >>= 1)
#pragma unroll
                for (int s = 0; s < 4; ++s) a[s] += __shfl_xor(a[s], off);
            if (lane == 0)
#pragma unroll
                for (int s = 0; s < 4; ++s) dstat[2 + s] = a[s];
        }
        __syncthreads();
    }

    if (tid < 3 * NPAT) {
        const double m0 = dstat[2] / (3.0 * (double)CNT);
        const double v0 = dstat[3] / (3.0 * (double)CNT) - m0 * m0;
        const double m1 = dstat[4] / (3.0 * (double)CNT);
        const double v1 = dstat[5] / (3.0 * (double)CNT) - m1 * m1;
        const float sc0 = go[0] * rsqrtf((float)v0 + EPS);
        const float sc1 = go[1] * rsqrtf((float)v1 + EPS);
        out_tab[tid * 2 + 0] = sc0 * (spre0[tid] - (float)m0) + beo[0];
        out_tab[tid * 2 + 1] = sc1 * (spre1[tid] - (float)m1) + beo[1];
    }
}

// ---------------- Kernel C: recompute patterns, write final output -------------
__global__ __launch_bounds__(256) void k_write(const float* __restrict__ x,
                                               const int* __restrict__ perms,
                                               const float* __restrict__ out_tab,
                                               float* __restrict__ out) {
    __shared__ unsigned char xb[SEQL];
    __shared__ unsigned char xbI[SEQL];
    __shared__ float tb[3 * NPAT * 2];
    const int b = blockIdx.x, tid = threadIdx.x;
    for (int i = tid; i < 3 * NPAT * 2; i += 256) tb[i] = out_tab[i];
    const float* xr = x + (size_t)b * SEQL;
    const int* pr = perms + (size_t)b * SEQL;
    for (int i = tid; i < SEQL; i += 256) xb[i] = xr[i] > 0.5f ? 1 : 0;
    __syncthreads();
    for (int i = tid; i < SEQL; i += 256) xbI[i] = xb[pr[i]];
    __syncthreads();
    float* ob = out + (size_t)b * (3 * SEQL * 2);
    for (int t = tid; t < SEQL; t += 256) {
        const int qd = pat_q(xb, t);
        const int qp = pat_q(xbI, t);
        const float2 v0 = *(const float2*)&tb[(0 * NPAT + qd) * 2];
        const float2 v1 = *(const float2*)&tb[(1 * NPAT + qd) * 2];
        const float2 v2 = *(const float2*)&tb[(2 * NPAT + qp) * 2];
        float2* o = (float2*)(ob + (size_t)t * 6);
        o[0] = v0; o[1] = v1; o[2] = v2;
    }
}

extern "C" void kernel_launch(void* const* d_in, const int* in_sizes, int n_in,
                              void* d_out, int out_size, void* d_ws, size_t ws_size,
                              hipStream_t stream) {
    (void)in_sizes; (void)n_in; (void)out_size; (void)ws_size;
    const float* x = (const float*)d_in[0];
    const int* perms = (const int*)d_in[1];

    // ws layout: [0,1280) u32 hist[320]; [1280,3200) f32 e_tab[480];
    //            [3200,7040) f32 out_tab[960]
    unsigned int* hist = (unsigned int*)d_ws;
    float* e_tab  = (float*)((char*)d_ws + 1280);
    float* out_tab = (float*)((char*)d_ws + 3200);

    hipMemsetAsync(d_ws, 0, 1280, stream);
    k_hist<<<BATCH, 256, 0, stream>>>(x, perms, hist);

    PtrPack pk;
    for (int j = 0; j < 3; ++j)
        for (int s = 0; s < 6; ++s)
            pk.p[6 * j + s] = (const float*)d_in[2 + 6 * j + s];
    k_etab<<<120, 256, 0, stream>>>(pk, hist, e_tab);

    k_outtab<<<1, 1024, 0, stream>>>(hist, e_tab,
                                     (const float*)d_in[20],  // Wm
                                     (const float*)d_in[22],  // gm
                                     (const float*)d_in[23],  // bem
                                     (const float*)d_in[24],  // Wo
                                     (const float*)d_in[25],  // bo
                                     (const float*)d_in[26],  // go
                                     (const float*)d_in[27],  // beo
                                     out_tab);

    k_write<<<BATCH, 256, 0, stream>>>(x, perms, out_tab, (float*)d_out);
}